// Round 1
// baseline (173.942 us; speedup 1.0000x reference)
//
#include <hip/hip_runtime.h>
#include <stdint.h>

typedef __bf16 bf16_t;
typedef __bf16 bf16x8 __attribute__((ext_vector_type(8)));
typedef float f32x4 __attribute__((ext_vector_type(4)));
typedef float f32x16 __attribute__((ext_vector_type(16)));
typedef unsigned int u32x2 __attribute__((ext_vector_type(2)));

#define DEV __device__ __forceinline__

DEV void gload_lds16(const void* g, void* lds) {
  __builtin_amdgcn_global_load_lds(
      (const __attribute__((address_space(1))) uint32_t*)g,
      (__attribute__((address_space(3))) uint32_t*)lds, 16, 0, 0);
}

DEV float fexp2(float x) {
#if __has_builtin(__builtin_amdgcn_exp2f)
  return __builtin_amdgcn_exp2f(x);
#else
  return exp2f(x);
#endif
}

DEV uint32_t pk_bf16(float a, float b) {
  uint32_t lo = (uint32_t)__builtin_bit_cast(uint16_t, (bf16_t)a);
  uint32_t hi = (uint32_t)__builtin_bit_cast(uint16_t, (bf16_t)b);
  return lo | (hi << 16);
}

// ---------------------------------------------------------------- K0: hs -> bf16
__global__ __launch_bounds__(256) void cvt_hs(const float* __restrict__ x,
                                              bf16_t* __restrict__ y) {
  int i = blockIdx.x * 256 + threadIdx.x;
  float4 v = ((const float4*)x)[i];
  ((uint2*)y)[i] = make_uint2(pk_bf16(v.x, v.y), pk_bf16(v.z, v.w));
}

// ------------------------------------------- K1: W[k][n] (x3) -> WT[n][k] bf16
__global__ __launch_bounds__(256) void cvt_w(const float* __restrict__ Wq,
                                             const float* __restrict__ Wk,
                                             const float* __restrict__ Wv,
                                             bf16_t* __restrict__ WT) {
  __shared__ float T[32][36];
  const int bx = blockIdx.x;   // n tile 0..71 (over 2304)
  const int by = blockIdx.y;   // k tile 0..23 (over 768)
  const int p = bx / 24;
  const float* W = (p == 0) ? Wq : ((p == 1) ? Wk : Wv);
  const int n0 = bx * 32, nn0 = n0 - p * 768, k0 = by * 32;
  const int t = threadIdx.x;
  {
    int r = t >> 3, c4 = (t & 7) * 4;
    float4 v = *(const float4*)&W[(size_t)(k0 + r) * 768 + nn0 + c4];
    T[r][c4 + 0] = v.x; T[r][c4 + 1] = v.y; T[r][c4 + 2] = v.z; T[r][c4 + 3] = v.w;
  }
  __syncthreads();
  {
    int nr = t >> 3, kc = (t & 7) * 4;
    uint32_t lo = pk_bf16(T[kc + 0][nr], T[kc + 1][nr]);
    uint32_t hi = pk_bf16(T[kc + 2][nr], T[kc + 3][nr]);
    *(uint2*)&WT[(size_t)(n0 + nr) * 768 + k0 + kc] = make_uint2(lo, hi);
  }
}

// ------------------------------------------------- K2: C[4096,2304] = A @ W (+b)
// K-projection output is pre-scaled by log2(e)/8 (softmax scale folded in).
__global__ __launch_bounds__(256) void gemm_qkv(
    const bf16_t* __restrict__ A, const bf16_t* __restrict__ Wt,
    const float* __restrict__ bq, const float* __restrict__ bk,
    const float* __restrict__ bv, bf16_t* __restrict__ Qo,
    bf16_t* __restrict__ Ko, bf16_t* __restrict__ VTo) {
  __shared__ __align__(16) char smem[34816];  // union: As+Bs (32KB) | Cs 128x136
  bf16_t* As = (bf16_t*)smem;
  bf16_t* Bs = As + 128 * 64;
  bf16_t* Cs = (bf16_t*)smem;
  const int bx = blockIdx.x;  // 0..17 (n)
  const int by = blockIdx.y;  // 0..31 (m)
  const int m0 = by * 128, n0 = bx * 128;
  const int tid = threadIdx.x, w = tid >> 6, lane = tid & 63;
  const int mw = (w & 1) * 64, nw = (w >> 1) * 64;
  const int quad = lane >> 4, col = lane & 15;

  f32x4 acc[4][4];
  for (int i = 0; i < 4; i++)
    for (int j = 0; j < 4; j++) acc[i][j] = (f32x4){0.f, 0.f, 0.f, 0.f};

  const int srow = w * 32 + (lane >> 3);
  const int scol = (lane & 7) * 8;
  const bf16_t* ag = A + (size_t)(m0 + srow) * 768 + scol;
  const bf16_t* bg = Wt + (size_t)(n0 + srow) * 768 + scol;

  for (int kk = 0; kk < 12; ++kk) {
    const int k0 = kk * 64;
    __syncthreads();
#pragma unroll
    for (int i = 0; i < 4; i++) {
      gload_lds16(ag + (size_t)i * 8 * 768 + k0, As + (w * 32 + i * 8) * 64);
      gload_lds16(bg + (size_t)i * 8 * 768 + k0, Bs + (w * 32 + i * 8) * 64);
    }
    __syncthreads();
#pragma unroll
    for (int ks = 0; ks < 2; ++ks) {
      bf16x8 af[4], bf[4];
#pragma unroll
      for (int mt = 0; mt < 4; ++mt)
        af[mt] = *(const bf16x8*)&As[(mw + mt * 16 + col) * 64 + ks * 32 + quad * 8];
#pragma unroll
      for (int nt = 0; nt < 4; ++nt)
        bf[nt] = *(const bf16x8*)&Bs[(nw + nt * 16 + col) * 64 + ks * 32 + quad * 8];
#pragma unroll
      for (int mt = 0; mt < 4; ++mt)
#pragma unroll
        for (int nt = 0; nt < 4; ++nt)
          acc[mt][nt] = __builtin_amdgcn_mfma_f32_16x16x32_bf16(
              af[mt], bf[nt], acc[mt][nt], 0, 0, 0);
    }
  }

  const int p = bx / 6;
  const float* bp = (p == 0) ? bq : ((p == 1) ? bk : bv);
  const float kscale = (p == 1) ? 0.18033688011112042f : 1.0f;  // log2(e)/sqrt(64)
  const int bb0 = m0 >> 11, s0 = m0 & 2047;
  __syncthreads();
  if (p < 2) {
#pragma unroll
    for (int nt = 0; nt < 4; nt++) {
      int n = nw + nt * 16 + col;
      float bias = bp[n0 + n - p * 768];
#pragma unroll
      for (int mt = 0; mt < 4; mt++)
#pragma unroll
        for (int r = 0; r < 4; r++) {
          int m = mw + mt * 16 + quad * 4 + r;
          Cs[m * 136 + n] = (bf16_t)((acc[mt][nt][r] + bias) * kscale);
        }
    }
    __syncthreads();
    bf16_t* dst = (p == 0) ? Qo : Ko;
#pragma unroll
    for (int i = 0; i < 8; i++) {
      int idx = i * 256 + tid;
      int m = idx >> 4, c = idx & 15;
      bf16x8 v = *(const bf16x8*)&Cs[m * 136 + c * 8];
      int nn = n0 - p * 768 + c * 8;
      int hq = nn >> 6, hd = nn & 63;
      *(bf16x8*)&dst[(size_t)((bb0 * 12 + hq) * 2048 + s0 + m) * 64 + hd] = v;
    }
  } else {
#pragma unroll
    for (int nt = 0; nt < 4; nt++) {
      int n = nw + nt * 16 + col;
      float bias = bp[n0 + n - 1536];
#pragma unroll
      for (int mt = 0; mt < 4; mt++)
#pragma unroll
        for (int r = 0; r < 4; r++) {
          int m = mw + mt * 16 + quad * 4 + r;
          Cs[n * 136 + m] = (bf16_t)(acc[mt][nt][r] + bias);
        }
    }
    __syncthreads();
#pragma unroll
    for (int i = 0; i < 8; i++) {
      int idx = i * 256 + tid;
      int n = idx >> 4, c = idx & 15;
      bf16x8 v = *(const bf16x8*)&Cs[n * 136 + c * 8];
      int nn = n0 - 1536 + n;
      int hq = nn >> 6, hd = nn & 63;
      *(bf16x8*)&VTo[((size_t)(bb0 * 12 + hq) * 64 + hd) * 2048 + s0 + c * 8] = v;
    }
  }
}

// ---------------------------------------------------------------- K3: attention
// v6: latency-bound fixes on top of v5:
//   - 3-buffer K/V pipeline, prefetch 2 iters ahead, counted s_waitcnt vmcnt(8)
//     + raw s_barrier (never drain to 0 in steady state)  [T3/T4]
//   - XCD-aware 1-D grid swizzle: id&7 -> XCD owns 3 consecutive bh
//     (96 blocks = 3/CU balanced; per-XCD K/V working set 1.5MB < 4MB L2)
//   - cross-half P exchange via v_permlane32_swap_b32 (1 swap fills both quad
//     words for both halves) instead of 8x ds_bpermute + cndmask selects [T12]
//   - l accumulated in 4 partials (chain depth 32 -> 8)
//   - s_setprio(1) around MFMA clusters [T5]
__global__ __launch_bounds__(128) void attn(const bf16_t* __restrict__ Q,
                                            const bf16_t* __restrict__ K,
                                            const bf16_t* __restrict__ VT,
                                            float* __restrict__ out) {
  __shared__ bf16_t Kl[3][64 * 64];   // [key][d], 16B chunks XOR-swizzled by row&7
  __shared__ bf16_t Vl[3][64 * 64];   // [d][key], same swizzle
  const int id = blockIdx.x;          // 0..767
  const int r = id >> 3;              // 0..95
  const int bh = (id & 7) * 3 + (r >> 5);
  const int qt = r & 31;
  const int b = bh / 12, head = bh % 12;
  const int tid = threadIdx.x, wv = tid >> 6, lane = tid & 63;
  const int lq = lane & 31, half = lane >> 5;
  const int q0 = qt * 64 + wv * 32;

  bf16x8 qf[4];  // B-frags of Q^T (per-lane query = lq), register resident
#pragma unroll
  for (int ks = 0; ks < 4; ++ks)
    qf[ks] = *(const bf16x8*)&Q[(size_t)(bh * 2048 + q0 + lq) * 64 + ks * 16 + half * 8];

  f32x16 oacc[2];  // [d-tile], O^T layout: col=q (lane), rows=d
  for (int i = 0; i < 16; i++) { oacc[0][i] = 0.f; oacc[1][i] = 0.f; }
  float l0 = 0.f, l1 = 0.f, l2 = 0.f, l3 = 0.f;  // partial denominators

  const bf16_t* gK = K + (size_t)bh * 2048 * 64;
  const bf16_t* gV = VT + (size_t)bh * 64 * 2048;
  const int srow = lane >> 3, scc = lane & 7;
  const int cg = scc ^ srow;  // swizzle col, invariant (row&7 == srow for all i)
  const bf16_t* gKb = gK + srow * 64 + cg * 8;    // + kb*4096 + i*512
  const bf16_t* gVb = gV + srow * 2048 + cg * 8;  // + i*16384 + kb*64

  auto stage = [&](int kb, int buf) {
    if (wv == 0) {
#pragma unroll
      for (int i = 0; i < 8; i++)
        gload_lds16(gKb + kb * 4096 + i * 512, &Kl[buf][i * 512]);
    } else {
#pragma unroll
      for (int i = 0; i < 8; i++)
        gload_lds16(gVb + i * 16384 + kb * 64, &Vl[buf][i * 512]);
    }
  };

  stage(0, 0);
  stage(1, 1);
  asm volatile("s_waitcnt vmcnt(8)" ::: "memory");  // buffer 0 ready; 1 in flight
  __builtin_amdgcn_s_barrier();
  asm volatile("" ::: "memory");

  int bb = 0, rb = 2;  // read buffer, write buffer ((kb+2)%3)
  for (int kb = 0; kb < 32; ++kb) {
    if (kb < 30) stage(kb + 2, rb);  // 2-deep prefetch, in flight across barriers

    // S^T[key][q] = K_blk @ Q^T   (K pre-scaled by log2e/8 at projection)
    f32x16 sacc[2];
    for (int i = 0; i < 16; i++) { sacc[0][i] = 0.f; sacc[1][i] = 0.f; }
    __builtin_amdgcn_s_setprio(1);
#pragma unroll
    for (int t = 0; t < 2; t++) {
      const int row = t * 32 + lq;
#pragma unroll
      for (int ks = 0; ks < 4; ++ks) {
        bf16x8 kf = *(const bf16x8*)&Kl[bb][row * 64 + (((2 * ks + half) ^ (row & 7)) * 8)];
        sacc[t] = __builtin_amdgcn_mfma_f32_32x32x16_bf16(kf, qf[ks], sacc[t], 0, 0, 0);
      }
    }
    __builtin_amdgcn_s_setprio(0);

    // P = exp2(S) (fixed max), l in 4 partial chains
#pragma unroll
    for (int t = 0; t < 2; t++)
#pragma unroll
      for (int rr = 0; rr < 16; rr++) sacc[t][rr] = fexp2(sacc[t][rr]);
#pragma unroll
    for (int rr = 0; rr < 16; rr += 4) {
      l0 += sacc[0][rr + 0] + sacc[1][rr + 0];
      l1 += sacc[0][rr + 1] + sacc[1][rr + 1];
      l2 += sacc[0][rr + 2] + sacc[1][rr + 2];
      l3 += sacc[0][rr + 3] + sacc[1][rr + 3];
    }

    // pack quads: pkq[t][g] = keys t*32 + 8g + 4*half + {0..3}, as 2x u32
    uint32_t pkq[2][4][2];
#pragma unroll
    for (int t = 0; t < 2; t++)
#pragma unroll
      for (int g = 0; g < 4; g++) {
        pkq[t][g][0] = pk_bf16(sacc[t][4 * g + 0], sacc[t][4 * g + 1]);
        pkq[t][g][1] = pk_bf16(sacc[t][4 * g + 2], sacc[t][4 * g + 3]);
      }

    // cross-half exchange -> B-operand frags. permlane32_swap(Y,X):
    //   Y' = {Y_lo, X_lo}  -> parity-0 quad word (elems 0-3) for both halves
    //   X' = {Y_hi, X_hi}  -> parity-1 quad word (elems 4-7) for both halves
    bf16x8 pfrag[4];
#pragma unroll
    for (int t = 0; t < 2; t++)
#pragma unroll
      for (int e = 0; e < 2; e++) {
        union { uint32_t u[4]; bf16x8 v; } F;
#pragma unroll
        for (int wd = 0; wd < 2; wd++) {
#if __has_builtin(__builtin_amdgcn_permlane32_swap)
          u32x2 sw = __builtin_amdgcn_permlane32_swap(pkq[t][2 * e][wd],
                                                      pkq[t][2 * e + 1][wd],
                                                      false, false);
          F.u[wd] = sw.x;
          F.u[2 + wd] = sw.y;
#else
          uint32_t s = half ? pkq[t][2 * e][wd] : pkq[t][2 * e + 1][wd];
          uint32_t rx = __shfl_xor(s, 32);
          uint32_t ow = half ? pkq[t][2 * e + 1][wd] : pkq[t][2 * e][wd];
          F.u[wd] = half ? rx : ow;
          F.u[2 + wd] = half ? ow : rx;
#endif
        }
        pfrag[2 * t + e] = F.v;
      }

    // O^T += V^T @ P^T  (A = V frags from LDS, B = pfrag)
    __builtin_amdgcn_s_setprio(1);
#pragma unroll
    for (int c = 0; c < 4; c++) {
#pragma unroll
      for (int dt = 0; dt < 2; dt++) {
        const int vr = dt * 32 + lq;
        bf16x8 vf = *(const bf16x8*)&Vl[bb][vr * 64 + (((2 * c + half) ^ (vr & 7)) * 8)];
        oacc[dt] = __builtin_amdgcn_mfma_f32_32x32x16_bf16(vf, pfrag[c], oacc[dt], 0, 0, 0);
      }
    }
    __builtin_amdgcn_s_setprio(0);

    // counted wait: keep newest stage batch (8 loads) in flight across barrier
    if (kb < 30) {
      asm volatile("s_waitcnt vmcnt(8)" ::: "memory");
    } else if (kb == 30) {
      asm volatile("s_waitcnt vmcnt(0)" ::: "memory");
    }
    if (kb < 31) {
      __builtin_amdgcn_s_barrier();
      asm volatile("" ::: "memory");
    }
    bb = (bb == 2) ? 0 : bb + 1;
    rb = (rb == 2) ? 0 : rb + 1;
  }

  // epilogue: l combine, O^T -> out[q][d] via per-wave LDS transpose
  float l_own = (l0 + l1) + (l2 + l3);
  float l_tot = l_own + __shfl_xor(l_own, 32);
  float inv = 1.0f / l_tot;
  __syncthreads();  // all K/V reads done; reuse Kl[wv] as 32x64 fp32 scratch
  float* Of = (float*)&Kl[wv][0];
#pragma unroll
  for (int dt = 0; dt < 2; dt++)
#pragma unroll
    for (int rr = 0; rr < 16; rr++) {
      int d = dt * 32 + (rr & 3) + 8 * (rr >> 2) + 4 * half;
      int g = d >> 2, wd = d & 3;
      Of[lq * 64 + ((g ^ (lq & 15)) * 4) + wd] = oacc[dt][rr] * inv;
    }
  float* ob = out + ((size_t)b * 2048 + q0) * 768 + head * 64;
#pragma unroll
  for (int i = 0; i < 8; i++) {
    int idx = i * 64 + lane;
    int q = idx >> 4, c = idx & 15;
    f32x4 v = *(f32x4*)&Of[q * 64 + ((c ^ (q & 15)) * 4)];
    *(f32x4*)&ob[(size_t)q * 768 + c * 4] = v;
  }
}

// -------------------------------------------------------------------- launcher
extern "C" void kernel_launch(void* const* d_in, const int* in_sizes, int n_in,
                              void* d_out, int out_size, void* d_ws, size_t ws_size,
                              hipStream_t stream) {
  const float* hs = (const float*)d_in[0];
  const float* Wq = (const float*)d_in[1];
  const float* bq = (const float*)d_in[2];
  const float* Wk = (const float*)d_in[3];
  const float* bk = (const float*)d_in[4];
  const float* Wv = (const float*)d_in[5];
  const float* bv = (const float*)d_in[6];
  float* out = (float*)d_out;

  char* w = (char*)d_ws;
  bf16_t* hsb = (bf16_t*)w; w += (size_t)4096 * 768 * 2;
  bf16_t* wtb = (bf16_t*)w; w += (size_t)2304 * 768 * 2;
  bf16_t* Qb  = (bf16_t*)w; w += (size_t)24 * 2048 * 64 * 2;
  bf16_t* Kb  = (bf16_t*)w; w += (size_t)24 * 2048 * 64 * 2;
  bf16_t* VTb = (bf16_t*)w;                                 // total ~29 MB

  hipLaunchKernelGGL(cvt_hs, dim3(3072), dim3(256), 0, stream, hs, hsb);
  hipLaunchKernelGGL(cvt_w, dim3(72, 24), dim3(256), 0, stream, Wq, Wk, Wv, wtb);
  hipLaunchKernelGGL(gemm_qkv, dim3(18, 32), dim3(256), 0, stream, hsb, wtb, bq,
                     bk, bv, Qb, Kb, VTb);
  hipLaunchKernelGGL(attn, dim3(768), dim3(128), 0, stream, Qb, Kb, VTb, out);
}

// Round 2
// 160.792 us; speedup vs baseline: 1.0818x; 1.0818x over previous
//
#include <hip/hip_runtime.h>
#include <stdint.h>

typedef __bf16 bf16_t;
typedef __bf16 bf16x8 __attribute__((ext_vector_type(8)));
typedef float f32x4 __attribute__((ext_vector_type(4)));
typedef float f32x16 __attribute__((ext_vector_type(16)));
typedef unsigned int u32x2 __attribute__((ext_vector_type(2)));

#define DEV __device__ __forceinline__

DEV void gload_lds16(const void* g, void* lds) {
  __builtin_amdgcn_global_load_lds(
      (const __attribute__((address_space(1))) uint32_t*)g,
      (__attribute__((address_space(3))) uint32_t*)lds, 16, 0, 0);
}

DEV float fexp2(float x) {
#if __has_builtin(__builtin_amdgcn_exp2f)
  return __builtin_amdgcn_exp2f(x);
#else
  return exp2f(x);
#endif
}

DEV uint32_t pk_bf16(float a, float b) {
  uint32_t lo = (uint32_t)__builtin_bit_cast(uint16_t, (bf16_t)a);
  uint32_t hi = (uint32_t)__builtin_bit_cast(uint16_t, (bf16_t)b);
  return lo | (hi << 16);
}

// ---------------------------------------------------------------- K0: hs -> bf16
__global__ __launch_bounds__(256) void cvt_hs(const float* __restrict__ x,
                                              bf16_t* __restrict__ y) {
  int i = blockIdx.x * 256 + threadIdx.x;
  float4 v = ((const float4*)x)[i];
  ((uint2*)y)[i] = make_uint2(pk_bf16(v.x, v.y), pk_bf16(v.z, v.w));
}

// ------------------------------------------- K1: W[k][n] (x3) -> WT[n][k] bf16
__global__ __launch_bounds__(256) void cvt_w(const float* __restrict__ Wq,
                                             const float* __restrict__ Wk,
                                             const float* __restrict__ Wv,
                                             bf16_t* __restrict__ WT) {
  __shared__ float T[32][36];
  const int bx = blockIdx.x;   // n tile 0..71 (over 2304)
  const int by = blockIdx.y;   // k tile 0..23 (over 768)
  const int p = bx / 24;
  const float* W = (p == 0) ? Wq : ((p == 1) ? Wk : Wv);
  const int n0 = bx * 32, nn0 = n0 - p * 768, k0 = by * 32;
  const int t = threadIdx.x;
  {
    int r = t >> 3, c4 = (t & 7) * 4;
    float4 v = *(const float4*)&W[(size_t)(k0 + r) * 768 + nn0 + c4];
    T[r][c4 + 0] = v.x; T[r][c4 + 1] = v.y; T[r][c4 + 2] = v.z; T[r][c4 + 3] = v.w;
  }
  __syncthreads();
  {
    int nr = t >> 3, kc = (t & 7) * 4;
    uint32_t lo = pk_bf16(T[kc + 0][nr], T[kc + 1][nr]);
    uint32_t hi = pk_bf16(T[kc + 2][nr], T[kc + 3][nr]);
    *(uint2*)&WT[(size_t)(n0 + nr) * 768 + k0 + kc] = make_uint2(lo, hi);
  }
}

// ------------------------------------------------- K2: C[4096,2304] = A @ W (+b)
// K-projection output is pre-scaled by log2(e)/8 (softmax scale folded in).
__global__ __launch_bounds__(256) void gemm_qkv(
    const bf16_t* __restrict__ A, const bf16_t* __restrict__ Wt,
    const float* __restrict__ bq, const float* __restrict__ bk,
    const float* __restrict__ bv, bf16_t* __restrict__ Qo,
    bf16_t* __restrict__ Ko, bf16_t* __restrict__ VTo) {
  __shared__ __align__(16) char smem[34816];  // union: As+Bs (32KB) | Cs 128x136
  bf16_t* As = (bf16_t*)smem;
  bf16_t* Bs = As + 128 * 64;
  bf16_t* Cs = (bf16_t*)smem;
  const int bx = blockIdx.x;  // 0..17 (n)
  const int by = blockIdx.y;  // 0..31 (m)
  const int m0 = by * 128, n0 = bx * 128;
  const int tid = threadIdx.x, w = tid >> 6, lane = tid & 63;
  const int mw = (w & 1) * 64, nw = (w >> 1) * 64;
  const int quad = lane >> 4, col = lane & 15;

  f32x4 acc[4][4];
  for (int i = 0; i < 4; i++)
    for (int j = 0; j < 4; j++) acc[i][j] = (f32x4){0.f, 0.f, 0.f, 0.f};

  const int srow = w * 32 + (lane >> 3);
  const int scol = (lane & 7) * 8;
  const bf16_t* ag = A + (size_t)(m0 + srow) * 768 + scol;
  const bf16_t* bg = Wt + (size_t)(n0 + srow) * 768 + scol;

  for (int kk = 0; kk < 12; ++kk) {
    const int k0 = kk * 64;
    __syncthreads();
#pragma unroll
    for (int i = 0; i < 4; i++) {
      gload_lds16(ag + (size_t)i * 8 * 768 + k0, As + (w * 32 + i * 8) * 64);
      gload_lds16(bg + (size_t)i * 8 * 768 + k0, Bs + (w * 32 + i * 8) * 64);
    }
    __syncthreads();
#pragma unroll
    for (int ks = 0; ks < 2; ++ks) {
      bf16x8 af[4], bf[4];
#pragma unroll
      for (int mt = 0; mt < 4; ++mt)
        af[mt] = *(const bf16x8*)&As[(mw + mt * 16 + col) * 64 + ks * 32 + quad * 8];
#pragma unroll
      for (int nt = 0; nt < 4; ++nt)
        bf[nt] = *(const bf16x8*)&Bs[(nw + nt * 16 + col) * 64 + ks * 32 + quad * 8];
#pragma unroll
      for (int mt = 0; mt < 4; ++mt)
#pragma unroll
        for (int nt = 0; nt < 4; ++nt)
          acc[mt][nt] = __builtin_amdgcn_mfma_f32_16x16x32_bf16(
              af[mt], bf[nt], acc[mt][nt], 0, 0, 0);
    }
  }

  const int p = bx / 6;
  const float* bp = (p == 0) ? bq : ((p == 1) ? bk : bv);
  const float kscale = (p == 1) ? 0.18033688011112042f : 1.0f;  // log2(e)/sqrt(64)
  const int bb0 = m0 >> 11, s0 = m0 & 2047;
  __syncthreads();
  if (p < 2) {
#pragma unroll
    for (int nt = 0; nt < 4; nt++) {
      int n = nw + nt * 16 + col;
      float bias = bp[n0 + n - p * 768];
#pragma unroll
      for (int mt = 0; mt < 4; mt++)
#pragma unroll
        for (int r = 0; r < 4; r++) {
          int m = mw + mt * 16 + quad * 4 + r;
          Cs[m * 136 + n] = (bf16_t)((acc[mt][nt][r] + bias) * kscale);
        }
    }
    __syncthreads();
    bf16_t* dst = (p == 0) ? Qo : Ko;
#pragma unroll
    for (int i = 0; i < 8; i++) {
      int idx = i * 256 + tid;
      int m = idx >> 4, c = idx & 15;
      bf16x8 v = *(const bf16x8*)&Cs[m * 136 + c * 8];
      int nn = n0 - p * 768 + c * 8;
      int hq = nn >> 6, hd = nn & 63;
      *(bf16x8*)&dst[(size_t)((bb0 * 12 + hq) * 2048 + s0 + m) * 64 + hd] = v;
    }
  } else {
#pragma unroll
    for (int nt = 0; nt < 4; nt++) {
      int n = nw + nt * 16 + col;
      float bias = bp[n0 + n - 1536];
#pragma unroll
      for (int mt = 0; mt < 4; mt++)
#pragma unroll
        for (int r = 0; r < 4; r++) {
          int m = mw + mt * 16 + quad * 4 + r;
          Cs[n * 136 + m] = (bf16_t)(acc[mt][nt][r] + bias);
        }
    }
    __syncthreads();
#pragma unroll
    for (int i = 0; i < 8; i++) {
      int idx = i * 256 + tid;
      int n = idx >> 4, c = idx & 15;
      bf16x8 v = *(const bf16x8*)&Cs[n * 136 + c * 8];
      int nn = n0 - 1536 + n;
      int hq = nn >> 6, hd = nn & 63;
      *(bf16x8*)&VTo[((size_t)(bb0 * 12 + hq) * 64 + hd) * 2048 + s0 + c * 8] = v;
    }
  }
}

// ---------------------------------------------------------------- K3: attention
// v7: split-K flash-decode restructure. Round-1 evidence: grid of 768 2-wave
// blocks = exactly 3 blocks/CU = 6 waves/CU (13% occ) and a ~4.6k-cycle
// per-iteration critical path that 1.5 waves/SIMD can't hide; memory pipeline
// fixes (counted vmcnt, XCD-L2 locality) were ~neutral. So: keep 768 blocks
// but make each 4 waves (128 queries sharing one staged K/V tile) and split
// the 2048 keys 2-way across blocks -> 12 waves/CU (3/SIMD), 16 iters/block.
// Blocks emit unnormalized partial O (fp32) + partial l; `combine` finishes.
__global__ __launch_bounds__(256, 3) void attn(const bf16_t* __restrict__ Q,
                                               const bf16_t* __restrict__ K,
                                               const bf16_t* __restrict__ VT,
                                               float* __restrict__ Op,
                                               float* __restrict__ lp) {
  __shared__ __align__(16) char smem[49152];
  bf16_t* Kl = (bf16_t*)smem;            // [3][64*64], XOR-swizzled by row&7
  bf16_t* Vl = (bf16_t*)(smem + 24576);  // [3][64*64], same swizzle
  const int id = blockIdx.x;             // 0..767
  const int rr0 = id >> 3;               // 0..95
  const int bh = (id & 7) * 3 + (rr0 >> 5);  // XCD id&7 owns 3 consecutive bh
  const int w5 = rr0 & 31;
  const int qt = w5 & 15, sp = w5 >> 4;  // q-tile, key-split half
  const int tid = threadIdx.x, wv = tid >> 6, lane = tid & 63;
  const int lq = lane & 31, half = lane >> 5;
  const int q0 = qt * 128 + wv * 32;

  bf16x8 qf[4];  // B-frags of Q^T (per-lane query = lq), register resident
#pragma unroll
  for (int ks = 0; ks < 4; ++ks)
    qf[ks] = *(const bf16x8*)&Q[(size_t)(bh * 2048 + q0 + lq) * 64 + ks * 16 + half * 8];

  f32x16 oacc[2];  // O^T partial: col=q (lane), rows=d
  for (int i = 0; i < 16; i++) { oacc[0][i] = 0.f; oacc[1][i] = 0.f; }
  float l0 = 0.f, l1 = 0.f, l2 = 0.f, l3 = 0.f;  // partial denominators

  const bf16_t* gK = K + (size_t)bh * 2048 * 64 + (size_t)sp * 1024 * 64;
  const bf16_t* gV = VT + (size_t)bh * 64 * 2048 + sp * 1024;
  const int srow = lane >> 3, scc = lane & 7;
  const int cg = scc ^ srow;  // inverse-swizzled source col (row&7 == srow)
  const bf16_t* gKb = gK + srow * 64 + cg * 8;    // + kb*4096 + ii*512
  const bf16_t* gVb = gV + srow * 2048 + cg * 8;  // + ii*16384 + kb*64
  const int kpart = (wv & 1) * 4;  // waves 0,1 stage K chunks 0-3/4-7; 2,3 V

  auto stage = [&](int kb, int buf) {
    if (wv < 2) {
#pragma unroll
      for (int i = 0; i < 4; i++) {
        int ii = kpart + i;
        gload_lds16(gKb + kb * 4096 + ii * 512, Kl + buf * 4096 + ii * 512);
      }
    } else {
#pragma unroll
      for (int i = 0; i < 4; i++) {
        int ii = kpart + i;
        gload_lds16(gVb + (size_t)ii * 16384 + kb * 64, Vl + buf * 4096 + ii * 512);
      }
    }
  };

  stage(0, 0);
  stage(1, 1);
  asm volatile("s_waitcnt vmcnt(4)" ::: "memory");  // buf0 (+Q) done; buf1 flying
  __builtin_amdgcn_s_barrier();
  asm volatile("" ::: "memory");

  int bb = 0, rb = 2;
  for (int kb = 0; kb < 16; ++kb) {
    if (kb < 14) stage(kb + 2, rb);  // 2-deep prefetch, in flight across barriers

    // S^T[key][q] = K_blk @ Q^T   (K pre-scaled by log2e/8 at projection)
    f32x16 sacc[2];
    for (int i = 0; i < 16; i++) { sacc[0][i] = 0.f; sacc[1][i] = 0.f; }
    __builtin_amdgcn_s_setprio(1);
#pragma unroll
    for (int t = 0; t < 2; t++) {
      const int row = t * 32 + lq;
#pragma unroll
      for (int ks = 0; ks < 4; ++ks) {
        bf16x8 kf = *(const bf16x8*)&Kl[bb * 4096 + row * 64 + (((2 * ks + half) ^ (row & 7)) * 8)];
        sacc[t] = __builtin_amdgcn_mfma_f32_32x32x16_bf16(kf, qf[ks], sacc[t], 0, 0, 0);
      }
    }
    __builtin_amdgcn_s_setprio(0);

    // P = exp2(S) (fixed max), l in 4 partial chains
#pragma unroll
    for (int t = 0; t < 2; t++)
#pragma unroll
      for (int rr = 0; rr < 16; rr++) sacc[t][rr] = fexp2(sacc[t][rr]);
#pragma unroll
    for (int rr = 0; rr < 16; rr += 4) {
      l0 += sacc[0][rr + 0] + sacc[1][rr + 0];
      l1 += sacc[0][rr + 1] + sacc[1][rr + 1];
      l2 += sacc[0][rr + 2] + sacc[1][rr + 2];
      l3 += sacc[0][rr + 3] + sacc[1][rr + 3];
    }

    // pack quads: pkq[t][g] = keys t*32 + 8g + 4*half + {0..3}, as 2x u32
    uint32_t pkq[2][4][2];
#pragma unroll
    for (int t = 0; t < 2; t++)
#pragma unroll
      for (int g = 0; g < 4; g++) {
        pkq[t][g][0] = pk_bf16(sacc[t][4 * g + 0], sacc[t][4 * g + 1]);
        pkq[t][g][1] = pk_bf16(sacc[t][4 * g + 2], sacc[t][4 * g + 3]);
      }

    // cross-half exchange -> B-operand frags via permlane32_swap
    bf16x8 pfrag[4];
#pragma unroll
    for (int t = 0; t < 2; t++)
#pragma unroll
      for (int e = 0; e < 2; e++) {
        union { uint32_t u[4]; bf16x8 v; } F;
#pragma unroll
        for (int wd = 0; wd < 2; wd++) {
#if __has_builtin(__builtin_amdgcn_permlane32_swap)
          u32x2 sw = __builtin_amdgcn_permlane32_swap(pkq[t][2 * e][wd],
                                                      pkq[t][2 * e + 1][wd],
                                                      false, false);
          F.u[wd] = sw.x;
          F.u[2 + wd] = sw.y;
#else
          uint32_t s = half ? pkq[t][2 * e][wd] : pkq[t][2 * e + 1][wd];
          uint32_t rx = __shfl_xor(s, 32);
          uint32_t ow = half ? pkq[t][2 * e + 1][wd] : pkq[t][2 * e][wd];
          F.u[wd] = half ? rx : ow;
          F.u[2 + wd] = half ? ow : rx;
#endif
        }
        pfrag[2 * t + e] = F.v;
      }

    // O^T += V^T @ P^T  (A = V frags from LDS, B = pfrag)
    __builtin_amdgcn_s_setprio(1);
#pragma unroll
    for (int c = 0; c < 4; c++) {
#pragma unroll
      for (int dt = 0; dt < 2; dt++) {
        const int vr = dt * 32 + lq;
        bf16x8 vf = *(const bf16x8*)&Vl[bb * 4096 + vr * 64 + (((2 * c + half) ^ (vr & 7)) * 8)];
        oacc[dt] = __builtin_amdgcn_mfma_f32_32x32x16_bf16(vf, pfrag[c], oacc[dt], 0, 0, 0);
      }
    }
    __builtin_amdgcn_s_setprio(0);

    // counted wait: keep newest stage batch (4 loads/wave) in flight
    if (kb < 14) {
      asm volatile("s_waitcnt vmcnt(4)" ::: "memory");
    } else if (kb == 14) {
      asm volatile("s_waitcnt vmcnt(0)" ::: "memory");
    }
    if (kb < 15) {
      __builtin_amdgcn_s_barrier();
      asm volatile("" ::: "memory");
    }
    bb = (bb == 2) ? 0 : bb + 1;
    rb = (rb == 2) ? 0 : rb + 1;
  }

  // epilogue: partial l + unnormalized partial O^T -> Op[q][d] rows
  float l_own = (l0 + l1) + (l2 + l3);
  float l_tot = l_own + __shfl_xor(l_own, 32);
  __syncthreads();  // all K/V reads done; smem becomes 4x 8KB f32 scratch
  float* Of = (float*)smem + wv * 2048;
#pragma unroll
  for (int dt = 0; dt < 2; dt++)
#pragma unroll
    for (int rr = 0; rr < 16; rr++) {
      int d = dt * 32 + (rr & 3) + 8 * (rr >> 2) + 4 * half;
      int g = d >> 2, wd = d & 3;
      Of[lq * 64 + ((g ^ (lq & 15)) * 4) + wd] = oacc[dt][rr];
    }
  if (half == 0) lp[((size_t)sp * 24 + bh) * 2048 + q0 + lq] = l_tot;
  float* ob = Op + (((size_t)sp * 24 + bh) * 2048 + q0) * 64;
#pragma unroll
  for (int i = 0; i < 8; i++) {
    int idx = i * 64 + lane;
    int qq = idx >> 4, c = idx & 15;
    f32x4 v = *(f32x4*)&Of[qq * 64 + ((c ^ (qq & 15)) * 4)];
    *(f32x4*)&ob[(size_t)qq * 64 + c * 4] = v;
  }
}

// ------------------------------------------------- K4: combine split-K partials
// out[b][q][h*64+d] = (Op0 + Op1) / (l0 + l1), with head-merge transpose.
__global__ __launch_bounds__(256) void combine(const float* __restrict__ Op,
                                               const float* __restrict__ lp,
                                               float* __restrict__ out) {
  int g = blockIdx.x * 256 + threadIdx.x;  // over 24*2048*16 = 786432
  int bh = g >> 15;
  int rem = g & 32767;
  int q = rem >> 4, c = rem & 15;
  const size_t plane = (size_t)24 * 2048 * 64;
  size_t o0 = ((size_t)bh * 2048 + q) * 64 + c * 4;
  f32x4 a = *(const f32x4*)&Op[o0];
  f32x4 b2 = *(const f32x4*)&Op[plane + o0];
  float l = lp[bh * 2048 + q] + lp[24 * 2048 + bh * 2048 + q];
  float inv = 1.0f / l;
  int b = bh / 12, head = bh % 12;
  f32x4 r;
#pragma unroll
  for (int j = 0; j < 4; j++) r[j] = (a[j] + b2[j]) * inv;
  *(f32x4*)&out[((size_t)b * 2048 + q) * 768 + head * 64 + c * 4] = r;
}

// -------------------------------------------------------------------- launcher
extern "C" void kernel_launch(void* const* d_in, const int* in_sizes, int n_in,
                              void* d_out, int out_size, void* d_ws, size_t ws_size,
                              hipStream_t stream) {
  const float* hs = (const float*)d_in[0];
  const float* Wq = (const float*)d_in[1];
  const float* bq = (const float*)d_in[2];
  const float* Wk = (const float*)d_in[3];
  const float* bk = (const float*)d_in[4];
  const float* Wv = (const float*)d_in[5];
  const float* bv = (const float*)d_in[6];
  float* out = (float*)d_out;

  char* w = (char*)d_ws;
  bf16_t* hsb = (bf16_t*)w; w += (size_t)4096 * 768 * 2;
  bf16_t* wtb = (bf16_t*)w; w += (size_t)2304 * 768 * 2;
  bf16_t* Qb  = (bf16_t*)w; w += (size_t)24 * 2048 * 64 * 2;
  bf16_t* Kb  = (bf16_t*)w; w += (size_t)24 * 2048 * 64 * 2;
  bf16_t* VTb = (bf16_t*)w; w += (size_t)24 * 2048 * 64 * 2;
  float* Opw  = (float*)w;  w += (size_t)2 * 24 * 2048 * 64 * 4;  // 25.2 MB
  float* lpw  = (float*)w;                                        // 0.39 MB

  hipLaunchKernelGGL(cvt_hs, dim3(3072), dim3(256), 0, stream, hs, hsb);
  hipLaunchKernelGGL(cvt_w, dim3(72, 24), dim3(256), 0, stream, Wq, Wk, Wv, wtb);
  hipLaunchKernelGGL(gemm_qkv, dim3(18, 32), dim3(256), 0, stream, hsb, wtb, bq,
                     bk, bv, Qb, Kb, VTb);
  hipLaunchKernelGGL(attn, dim3(768), dim3(256), 0, stream, Qb, Kb, VTb, Opw, lpw);
  hipLaunchKernelGGL(combine, dim3(3072), dim3(256), 0, stream, Opw, lpw, out);
}

// Round 3
// 147.819 us; speedup vs baseline: 1.1767x; 1.0878x over previous
//
#include <hip/hip_runtime.h>
#include <stdint.h>

typedef __bf16 bf16_t;
typedef __bf16 bf16x8 __attribute__((ext_vector_type(8)));
typedef float f32x4 __attribute__((ext_vector_type(4)));
typedef float f32x16 __attribute__((ext_vector_type(16)));
typedef unsigned int u32x2 __attribute__((ext_vector_type(2)));

#define DEV __device__ __forceinline__

DEV void gload_lds16(const void* g, void* lds) {
  __builtin_amdgcn_global_load_lds(
      (const __attribute__((address_space(1))) uint32_t*)g,
      (__attribute__((address_space(3))) uint32_t*)lds, 16, 0, 0);
}

DEV float fexp2(float x) {
#if __has_builtin(__builtin_amdgcn_exp2f)
  return __builtin_amdgcn_exp2f(x);
#else
  return exp2f(x);
#endif
}

DEV uint32_t pk_bf16(float a, float b) {
  uint32_t lo = (uint32_t)__builtin_bit_cast(uint16_t, (bf16_t)a);
  uint32_t hi = (uint32_t)__builtin_bit_cast(uint16_t, (bf16_t)b);
  return lo | (hi << 16);
}

// ---------------------------------------------------------------- K0: hs -> bf16
__global__ __launch_bounds__(256) void cvt_hs(const float* __restrict__ x,
                                              bf16_t* __restrict__ y) {
  int i = blockIdx.x * 256 + threadIdx.x;
  float4 v = ((const float4*)x)[i];
  ((uint2*)y)[i] = make_uint2(pk_bf16(v.x, v.y), pk_bf16(v.z, v.w));
}

// ------------------------------------------- K1: W[k][n] (x3) -> WT[n][k] bf16
__global__ __launch_bounds__(256) void cvt_w(const float* __restrict__ Wq,
                                             const float* __restrict__ Wk,
                                             const float* __restrict__ Wv,
                                             bf16_t* __restrict__ WT) {
  __shared__ float T[32][36];
  const int bx = blockIdx.x;   // n tile 0..71 (over 2304)
  const int by = blockIdx.y;   // k tile 0..23 (over 768)
  const int p = bx / 24;
  const float* W = (p == 0) ? Wq : ((p == 1) ? Wk : Wv);
  const int n0 = bx * 32, nn0 = n0 - p * 768, k0 = by * 32;
  const int t = threadIdx.x;
  {
    int r = t >> 3, c4 = (t & 7) * 4;
    float4 v = *(const float4*)&W[(size_t)(k0 + r) * 768 + nn0 + c4];
    T[r][c4 + 0] = v.x; T[r][c4 + 1] = v.y; T[r][c4 + 2] = v.z; T[r][c4 + 3] = v.w;
  }
  __syncthreads();
  {
    int nr = t >> 3, kc = (t & 7) * 4;
    uint32_t lo = pk_bf16(T[kc + 0][nr], T[kc + 1][nr]);
    uint32_t hi = pk_bf16(T[kc + 2][nr], T[kc + 3][nr]);
    *(uint2*)&WT[(size_t)(n0 + nr) * 768 + k0 + kc] = make_uint2(lo, hi);
  }
}

// ------------------------------------------------- K2: C[4096,2304] = A @ W (+b)
// K-projection output is pre-scaled by log2(e)/8 (softmax scale folded in).
// v2: double-buffered LDS pipeline. Round-2 evidence: the old
// barrier/stage/barrier/compute loop exposed the full VMEM latency of every
// K-step (per-step ~3.8k cy vs ~0.5k cy of work; MfmaUtil 11.7%). Now
// stage(k+1) is issued before compute(k) and a single barrier per step drains
// it after the compute has flown -- latency hidden under MFMA + the second
// resident block. LDS 64KB (2 buffers, Cs unioned) -> 2 blocks/CU.
__global__ __launch_bounds__(256) void gemm_qkv(
    const bf16_t* __restrict__ A, const bf16_t* __restrict__ Wt,
    const float* __restrict__ bq, const float* __restrict__ bk,
    const float* __restrict__ bv, bf16_t* __restrict__ Qo,
    bf16_t* __restrict__ Ko, bf16_t* __restrict__ VTo) {
  __shared__ __align__(16) char smem[65536];  // 2 x (As 16K + Bs 16K); Cs union
  bf16_t* Cs = (bf16_t*)smem;  // 128x136 epilogue scratch
  const int bx = blockIdx.x;  // 0..17 (n)
  const int by = blockIdx.y;  // 0..31 (m)
  const int m0 = by * 128, n0 = bx * 128;
  const int tid = threadIdx.x, w = tid >> 6, lane = tid & 63;
  const int mw = (w & 1) * 64, nw = (w >> 1) * 64;
  const int quad = lane >> 4, col = lane & 15;

  f32x4 acc[4][4];
  for (int i = 0; i < 4; i++)
    for (int j = 0; j < 4; j++) acc[i][j] = (f32x4){0.f, 0.f, 0.f, 0.f};

  const int srow = w * 32 + (lane >> 3);
  const int scol = (lane & 7) * 8;
  const bf16_t* ag = A + (size_t)(m0 + srow) * 768 + scol;
  const bf16_t* bg = Wt + (size_t)(n0 + srow) * 768 + scol;

  auto stageg = [&](int kk, int bf) {
    const int k0 = kk * 64;
    bf16_t* dA = (bf16_t*)(smem + bf * 32768) + (w * 32) * 64;
    bf16_t* dB = (bf16_t*)(smem + bf * 32768 + 16384) + (w * 32) * 64;
#pragma unroll
    for (int i = 0; i < 4; i++) {
      gload_lds16(ag + (size_t)i * 8 * 768 + k0, dA + i * 8 * 64);
      gload_lds16(bg + (size_t)i * 8 * 768 + k0, dB + i * 8 * 64);
    }
  };

  stageg(0, 0);
  __syncthreads();  // one exposed drain at prologue only

  for (int kk = 0; kk < 12; ++kk) {
    const int bf = kk & 1;
    if (kk < 11) stageg(kk + 1, bf ^ 1);
    __builtin_amdgcn_sched_barrier(0);  // pin load issue ahead of compute
    const bf16_t* As = (const bf16_t*)(smem + bf * 32768);
    const bf16_t* Bs = (const bf16_t*)(smem + bf * 32768 + 16384);
#pragma unroll
    for (int ks = 0; ks < 2; ++ks) {
      bf16x8 af[4], bfr[4];
#pragma unroll
      for (int mt = 0; mt < 4; ++mt)
        af[mt] = *(const bf16x8*)&As[(mw + mt * 16 + col) * 64 + ks * 32 + quad * 8];
#pragma unroll
      for (int nt = 0; nt < 4; ++nt)
        bfr[nt] = *(const bf16x8*)&Bs[(nw + nt * 16 + col) * 64 + ks * 32 + quad * 8];
#pragma unroll
      for (int mt = 0; mt < 4; ++mt)
#pragma unroll
        for (int nt = 0; nt < 4; ++nt)
          acc[mt][nt] = __builtin_amdgcn_mfma_f32_16x16x32_bf16(
              af[mt], bfr[nt], acc[mt][nt], 0, 0, 0);
    }
    __syncthreads();  // publishes stage(kk+1); all reads of buf done
  }

  const int p = bx / 6;
  const float* bp = (p == 0) ? bq : ((p == 1) ? bk : bv);
  const float kscale = (p == 1) ? 0.18033688011112042f : 1.0f;  // log2(e)/sqrt(64)
  const int bb0 = m0 >> 11, s0 = m0 & 2047;
  if (p < 2) {
#pragma unroll
    for (int nt = 0; nt < 4; nt++) {
      int n = nw + nt * 16 + col;
      float bias = bp[n0 + n - p * 768];
#pragma unroll
      for (int mt = 0; mt < 4; mt++)
#pragma unroll
        for (int r = 0; r < 4; r++) {
          int m = mw + mt * 16 + quad * 4 + r;
          Cs[m * 136 + n] = (bf16_t)((acc[mt][nt][r] + bias) * kscale);
        }
    }
    __syncthreads();
    bf16_t* dst = (p == 0) ? Qo : Ko;
#pragma unroll
    for (int i = 0; i < 8; i++) {
      int idx = i * 256 + tid;
      int m = idx >> 4, c = idx & 15;
      bf16x8 v = *(const bf16x8*)&Cs[m * 136 + c * 8];
      int nn = n0 - p * 768 + c * 8;
      int hq = nn >> 6, hd = nn & 63;
      *(bf16x8*)&dst[(size_t)((bb0 * 12 + hq) * 2048 + s0 + m) * 64 + hd] = v;
    }
  } else {
#pragma unroll
    for (int nt = 0; nt < 4; nt++) {
      int n = nw + nt * 16 + col;
      float bias = bp[n0 + n - 1536];
#pragma unroll
      for (int mt = 0; mt < 4; mt++)
#pragma unroll
        for (int r = 0; r < 4; r++) {
          int m = mw + mt * 16 + quad * 4 + r;
          Cs[n * 136 + m] = (bf16_t)(acc[mt][nt][r] + bias);
        }
    }
    __syncthreads();
#pragma unroll
    for (int i = 0; i < 8; i++) {
      int idx = i * 256 + tid;
      int n = idx >> 4, c = idx & 15;
      bf16x8 v = *(const bf16x8*)&Cs[n * 136 + c * 8];
      int nn = n0 - 1536 + n;
      int hq = nn >> 6, hd = nn & 63;
      *(bf16x8*)&VTo[((size_t)(bb0 * 12 + hq) * 64 + hd) * 2048 + s0 + c * 8] = v;
    }
  }
}

// ---------------------------------------------------------------- K3: attention
// v7: split-K flash-decode. 768 4-wave blocks (128 q x 2 key-halves),
// 12 waves/CU, 16 iters/block, 3-buffer counted-vmcnt pipeline, permlane32
// P-exchange, fixed-max exp2 softmax. Partials combined by K4.
__global__ __launch_bounds__(256, 3) void attn(const bf16_t* __restrict__ Q,
                                               const bf16_t* __restrict__ K,
                                               const bf16_t* __restrict__ VT,
                                               float* __restrict__ Op,
                                               float* __restrict__ lp) {
  __shared__ __align__(16) char smem[49152];
  bf16_t* Kl = (bf16_t*)smem;            // [3][64*64], XOR-swizzled by row&7
  bf16_t* Vl = (bf16_t*)(smem + 24576);  // [3][64*64], same swizzle
  const int id = blockIdx.x;             // 0..767
  const int rr0 = id >> 3;               // 0..95
  const int bh = (id & 7) * 3 + (rr0 >> 5);  // XCD id&7 owns 3 consecutive bh
  const int w5 = rr0 & 31;
  const int qt = w5 & 15, sp = w5 >> 4;  // q-tile, key-split half
  const int tid = threadIdx.x, wv = tid >> 6, lane = tid & 63;
  const int lq = lane & 31, half = lane >> 5;
  const int q0 = qt * 128 + wv * 32;

  bf16x8 qf[4];  // B-frags of Q^T (per-lane query = lq), register resident
#pragma unroll
  for (int ks = 0; ks < 4; ++ks)
    qf[ks] = *(const bf16x8*)&Q[(size_t)(bh * 2048 + q0 + lq) * 64 + ks * 16 + half * 8];

  f32x16 oacc[2];  // O^T partial: col=q (lane), rows=d
  for (int i = 0; i < 16; i++) { oacc[0][i] = 0.f; oacc[1][i] = 0.f; }
  float l0 = 0.f, l1 = 0.f, l2 = 0.f, l3 = 0.f;  // partial denominators

  const bf16_t* gK = K + (size_t)bh * 2048 * 64 + (size_t)sp * 1024 * 64;
  const bf16_t* gV = VT + (size_t)bh * 64 * 2048 + sp * 1024;
  const int srow = lane >> 3, scc = lane & 7;
  const int cg = scc ^ srow;  // inverse-swizzled source col (row&7 == srow)
  const bf16_t* gKb = gK + srow * 64 + cg * 8;    // + kb*4096 + ii*512
  const bf16_t* gVb = gV + srow * 2048 + cg * 8;  // + ii*16384 + kb*64
  const int kpart = (wv & 1) * 4;  // waves 0,1 stage K chunks 0-3/4-7; 2,3 V

  auto stage = [&](int kb, int buf) {
    if (wv < 2) {
#pragma unroll
      for (int i = 0; i < 4; i++) {
        int ii = kpart + i;
        gload_lds16(gKb + kb * 4096 + ii * 512, Kl + buf * 4096 + ii * 512);
      }
    } else {
#pragma unroll
      for (int i = 0; i < 4; i++) {
        int ii = kpart + i;
        gload_lds16(gVb + (size_t)ii * 16384 + kb * 64, Vl + buf * 4096 + ii * 512);
      }
    }
  };

  stage(0, 0);
  stage(1, 1);
  asm volatile("s_waitcnt vmcnt(4)" ::: "memory");  // buf0 (+Q) done; buf1 flying
  __builtin_amdgcn_s_barrier();
  asm volatile("" ::: "memory");

  int bb = 0, rb = 2;
  for (int kb = 0; kb < 16; ++kb) {
    if (kb < 14) stage(kb + 2, rb);  // 2-deep prefetch, in flight across barriers

    // S^T[key][q] = K_blk @ Q^T   (K pre-scaled by log2e/8 at projection)
    f32x16 sacc[2];
    for (int i = 0; i < 16; i++) { sacc[0][i] = 0.f; sacc[1][i] = 0.f; }
    __builtin_amdgcn_s_setprio(1);
#pragma unroll
    for (int t = 0; t < 2; t++) {
      const int row = t * 32 + lq;
#pragma unroll
      for (int ks = 0; ks < 4; ++ks) {
        bf16x8 kf = *(const bf16x8*)&Kl[bb * 4096 + row * 64 + (((2 * ks + half) ^ (row & 7)) * 8)];
        sacc[t] = __builtin_amdgcn_mfma_f32_32x32x16_bf16(kf, qf[ks], sacc[t], 0, 0, 0);
      }
    }
    __builtin_amdgcn_s_setprio(0);

    // P = exp2(S) (fixed max), l in 4 partial chains
#pragma unroll
    for (int t = 0; t < 2; t++)
#pragma unroll
      for (int rr = 0; rr < 16; rr++) sacc[t][rr] = fexp2(sacc[t][rr]);
#pragma unroll
    for (int rr = 0; rr < 16; rr += 4) {
      l0 += sacc[0][rr + 0] + sacc[1][rr + 0];
      l1 += sacc[0][rr + 1] + sacc[1][rr + 1];
      l2 += sacc[0][rr + 2] + sacc[1][rr + 2];
      l3 += sacc[0][rr + 3] + sacc[1][rr + 3];
    }

    // pack quads: pkq[t][g] = keys t*32 + 8g + 4*half + {0..3}, as 2x u32
    uint32_t pkq[2][4][2];
#pragma unroll
    for (int t = 0; t < 2; t++)
#pragma unroll
      for (int g = 0; g < 4; g++) {
        pkq[t][g][0] = pk_bf16(sacc[t][4 * g + 0], sacc[t][4 * g + 1]);
        pkq[t][g][1] = pk_bf16(sacc[t][4 * g + 2], sacc[t][4 * g + 3]);
      }

    // cross-half exchange -> B-operand frags via permlane32_swap
    bf16x8 pfrag[4];
#pragma unroll
    for (int t = 0; t < 2; t++)
#pragma unroll
      for (int e = 0; e < 2; e++) {
        union { uint32_t u[4]; bf16x8 v; } F;
#pragma unroll
        for (int wd = 0; wd < 2; wd++) {
#if __has_builtin(__builtin_amdgcn_permlane32_swap)
          u32x2 sw = __builtin_amdgcn_permlane32_swap(pkq[t][2 * e][wd],
                                                      pkq[t][2 * e + 1][wd],
                                                      false, false);
          F.u[wd] = sw.x;
          F.u[2 + wd] = sw.y;
#else
          uint32_t s = half ? pkq[t][2 * e][wd] : pkq[t][2 * e + 1][wd];
          uint32_t rx = __shfl_xor(s, 32);
          uint32_t ow = half ? pkq[t][2 * e + 1][wd] : pkq[t][2 * e][wd];
          F.u[wd] = half ? rx : ow;
          F.u[2 + wd] = half ? ow : rx;
#endif
        }
        pfrag[2 * t + e] = F.v;
      }

    // O^T += V^T @ P^T  (A = V frags from LDS, B = pfrag)
    __builtin_amdgcn_s_setprio(1);
#pragma unroll
    for (int c = 0; c < 4; c++) {
#pragma unroll
      for (int dt = 0; dt < 2; dt++) {
        const int vr = dt * 32 + lq;
        bf16x8 vf = *(const bf16x8*)&Vl[bb * 4096 + vr * 64 + (((2 * c + half) ^ (vr & 7)) * 8)];
        oacc[dt] = __builtin_amdgcn_mfma_f32_32x32x16_bf16(vf, pfrag[c], oacc[dt], 0, 0, 0);
      }
    }
    __builtin_amdgcn_s_setprio(0);

    // counted wait: keep newest stage batch (4 loads/wave) in flight
    if (kb < 14) {
      asm volatile("s_waitcnt vmcnt(4)" ::: "memory");
    } else if (kb == 14) {
      asm volatile("s_waitcnt vmcnt(0)" ::: "memory");
    }
    if (kb < 15) {
      __builtin_amdgcn_s_barrier();
      asm volatile("" ::: "memory");
    }
    bb = (bb == 2) ? 0 : bb + 1;
    rb = (rb == 2) ? 0 : rb + 1;
  }

  // epilogue: partial l + unnormalized partial O^T -> Op[q][d] rows
  float l_own = (l0 + l1) + (l2 + l3);
  float l_tot = l_own + __shfl_xor(l_own, 32);
  __syncthreads();  // all K/V reads done; smem becomes 4x 8KB f32 scratch
  float* Of = (float*)smem + wv * 2048;
#pragma unroll
  for (int dt = 0; dt < 2; dt++)
#pragma unroll
    for (int rr = 0; rr < 16; rr++) {
      int d = dt * 32 + (rr & 3) + 8 * (rr >> 2) + 4 * half;
      int g = d >> 2, wd = d & 3;
      Of[lq * 64 + ((g ^ (lq & 15)) * 4) + wd] = oacc[dt][rr];
    }
  if (half == 0) lp[((size_t)sp * 24 + bh) * 2048 + q0 + lq] = l_tot;
  float* ob = Op + (((size_t)sp * 24 + bh) * 2048 + q0) * 64;
#pragma unroll
  for (int i = 0; i < 8; i++) {
    int idx = i * 64 + lane;
    int qq = idx >> 4, c = idx & 15;
    f32x4 v = *(f32x4*)&Of[qq * 64 + ((c ^ (qq & 15)) * 4)];
    *(f32x4*)&ob[(size_t)qq * 64 + c * 4] = v;
  }
}

// ------------------------------------------------- K4: combine split-K partials
// out[b][q][h*64+d] = (Op0 + Op1) / (l0 + l1), with head-merge transpose.
__global__ __launch_bounds__(256) void combine(const float* __restrict__ Op,
                                               const float* __restrict__ lp,
                                               float* __restrict__ out) {
  int g = blockIdx.x * 256 + threadIdx.x;  // over 24*2048*16 = 786432
  int bh = g >> 15;
  int rem = g & 32767;
  int q = rem >> 4, c = rem & 15;
  const size_t plane = (size_t)24 * 2048 * 64;
  size_t o0 = ((size_t)bh * 2048 + q) * 64 + c * 4;
  f32x4 a = *(const f32x4*)&Op[o0];
  f32x4 b2 = *(const f32x4*)&Op[plane + o0];
  float l = lp[bh * 2048 + q] + lp[24 * 2048 + bh * 2048 + q];
  float inv = 1.0f / l;
  int b = bh / 12, head = bh % 12;
  f32x4 r;
#pragma unroll
  for (int j = 0; j < 4; j++) r[j] = (a[j] + b2[j]) * inv;
  *(f32x4*)&out[((size_t)b * 2048 + q) * 768 + head * 64 + c * 4] = r;
}

// -------------------------------------------------------------------- launcher
extern "C" void kernel_launch(void* const* d_in, const int* in_sizes, int n_in,
                              void* d_out, int out_size, void* d_ws, size_t ws_size,
                              hipStream_t stream) {
  const float* hs = (const float*)d_in[0];
  const float* Wq = (const float*)d_in[1];
  const float* bq = (const float*)d_in[2];
  const float* Wk = (const float*)d_in[3];
  const float* bk = (const float*)d_in[4];
  const float* Wv = (const float*)d_in[5];
  const float* bv = (const float*)d_in[6];
  float* out = (float*)d_out;

  char* w = (char*)d_ws;
  bf16_t* hsb = (bf16_t*)w; w += (size_t)4096 * 768 * 2;
  bf16_t* wtb = (bf16_t*)w; w += (size_t)2304 * 768 * 2;
  bf16_t* Qb  = (bf16_t*)w; w += (size_t)24 * 2048 * 64 * 2;
  bf16_t* Kb  = (bf16_t*)w; w += (size_t)24 * 2048 * 64 * 2;
  bf16_t* VTb = (bf16_t*)w; w += (size_t)24 * 2048 * 64 * 2;
  float* Opw  = (float*)w;  w += (size_t)2 * 24 * 2048 * 64 * 4;  // 25.2 MB
  float* lpw  = (float*)w;                                        // 0.39 MB

  hipLaunchKernelGGL(cvt_hs, dim3(3072), dim3(256), 0, stream, hs, hsb);
  hipLaunchKernelGGL(cvt_w, dim3(72, 24), dim3(256), 0, stream, Wq, Wk, Wv, wtb);
  hipLaunchKernelGGL(gemm_qkv, dim3(18, 32), dim3(256), 0, stream, hsb, wtb, bq,
                     bk, bv, Qb, Kb, VTb);
  hipLaunchKernelGGL(attn, dim3(768), dim3(256), 0, stream, Qb, Kb, VTb, Opw, lpw);
  hipLaunchKernelGGL(combine, dim3(3072), dim3(256), 0, stream, Opw, lpw, out);
}